// Round 9
// baseline (248.593 us; speedup 1.0000x reference)
//
#include <hip/hip_runtime.h>

#define N_PIX    32768
#define DIM      64
#define K_CODES  1024
#define BPIX     256          // pixels per block
#define CHUNK    256          // codes per LDS chunk
#define NSPLIT   2            // K split across blocks (512 codes per split)

// ws layout: [0,4096) c2[1024] ; [4096, +512KiB) part float2[NSPLIT][N_PIX] ;
//            [4096+512KiB, +128KiB) idx[N_PIX]

__global__ __launch_bounds__(256) void c2_kernel(const float* __restrict__ cb,
                                                 float* __restrict__ c2) {
    int k = blockIdx.x * 256 + threadIdx.x;
    if (k >= K_CODES) return;
    const float* row = cb + k * DIM;
    float a0 = 0.f, a1 = 0.f, a2 = 0.f, a3 = 0.f;
#pragma unroll
    for (int d = 0; d < DIM; d += 4) {
        a0 = fmaf(row[d + 0], row[d + 0], a0);
        a1 = fmaf(row[d + 1], row[d + 1], a1);
        a2 = fmaf(row[d + 2], row[d + 2], a2);
        a3 = fmaf(row[d + 3], row[d + 3], a3);
    }
    c2[k] = (a0 + a1) + (a2 + a3);
}

// 512 threads = 8 waves (4 prow x 2 kcol), wave = 8wy x 8wx lanes.
// Thread tile 8 pix x 16 codes; codes scattered as 4 groups of 4
// (k = wc*128 + j*32 + wx*4) so every c-read b128 covers all 32 banks
// (conflict-free; wy-lanes broadcast). DS/FMA = 0.1875 float (vs 0.25 at 8x8)
// -> DS bound ~31us vs VALU 27us. Block tile 256 pix x 256 codes per chunk,
// 2 chunks; K split over 2 blocks -> grid 256 = 1 block/CU, 2 waves/SIMD.
__global__ __launch_bounds__(512, 2) void argmin_tile(const float* __restrict__ x,
                                                      const float* __restrict__ cb,
                                                      const float* __restrict__ c2,
                                                      float2* __restrict__ part) {
    __shared__ alignas(16) float xs[DIM * BPIX];     // 64 KB [d][p]
    __shared__ alignas(16) float cs[DIM * CHUNK];    // 64 KB [d][k]
    __shared__ float  xn[BPIX];                      // 1 KB
    __shared__ float2 red[2][BPIX];                  // 4 KB

    const int t      = threadIdx.x;
    const int blk    = blockIdx.x;
    const int ks     = blk & 1;           // K split 0/1
    const int pixblk = blk >> 1;          // 0..127
    const int p_base = pixblk * BPIX;
    const int bb     = p_base >> 10;
    const int hw0    = p_base & 1023;     // 0/256/512/768: block stays in batch

    const float4* x4  = reinterpret_cast<const float4*>(x);
    const float4* cb4 = reinterpret_cast<const float4*>(cb);

    // ---- prefetch chunk-0 codebook tile to regs (consumed after xs staging)
    float4 creg[8];
#pragma unroll
    for (int i = 0; i < 8; ++i) {
        int fidx = i * 512 + t;           // 0..4095
        int k = fidx & 255, dq = fidx >> 8;
        creg[i] = cb4[(size_t)(ks * 512 + k) * 16 + dq];
    }

    // ---- stage xs: [d][p], rows contiguous in x -> coalesced float4
#pragma unroll
    for (int i = 0; i < 8; ++i) {
        int fidx = i * 512 + t;
        int d = fidx >> 6, p4 = fidx & 63;
        reinterpret_cast<float4*>(xs)[d * 64 + p4] =
            x4[(size_t)bb * 16384 + (size_t)d * 256 + (hw0 >> 2) + p4];
    }
    __syncthreads();

    // ---- xn: EXACT tree of passing rounds (s[d%4] ascending, (s0+s1)+(s2+s3))
    if (t < BPIX) {
        float s0 = 0.f, s1 = 0.f, s2 = 0.f, s3 = 0.f;
#pragma unroll
        for (int d = 0; d < DIM; d += 4) {
            float v0 = xs[(d + 0) * BPIX + t];
            float v1 = xs[(d + 1) * BPIX + t];
            float v2 = xs[(d + 2) * BPIX + t];
            float v3 = xs[(d + 3) * BPIX + t];
            s0 = fmaf(v0, v0, s0);
            s1 = fmaf(v1, v1, s1);
            s2 = fmaf(v2, v2, s2);
            s3 = fmaf(v3, v3, s3);
        }
        xn[t] = (s0 + s1) + (s2 + s3);
    }

    // ---- wave decomposition
    const int lane = t & 63, w = t >> 6;
    const int wy = lane >> 3, wx = lane & 7;
    const int wr = w >> 1,    wc = w & 1;
    const int pl0 = wr * 64 + wy * 8;     // local pixel base (0..248)
    const int kb  = wc * 128;             // local code-half base
    const int wx4 = wx * 4;

    float bv[8]; int bk[8]; float xnr[8];
#pragma unroll
    for (int i = 0; i < 8; ++i) { bv[i] = 1e30f; bk[i] = 0; }

    float acc[8][16];

    for (int ch = 0; ch < 2; ++ch) {
        // write staged tile to cs[d][k] (k lane-fast b32 writes: 2-way, free)
#pragma unroll
        for (int i = 0; i < 8; ++i) {
            int fidx = i * 512 + t;
            int k = fidx & 255, dq = fidx >> 8;
            cs[(4 * dq + 0) * CHUNK + k] = creg[i].x;
            cs[(4 * dq + 1) * CHUNK + k] = creg[i].y;
            cs[(4 * dq + 2) * CHUNK + k] = creg[i].z;
            cs[(4 * dq + 3) * CHUNK + k] = creg[i].w;
        }
        if (ch == 0) {   // prefetch chunk 1 (hides under chunk-0 compute)
#pragma unroll
            for (int i = 0; i < 8; ++i) {
                int fidx = i * 512 + t;
                int k = fidx & 255, dq = fidx >> 8;
                creg[i] = cb4[(size_t)(ks * 512 + 256 + k) * 16 + dq];
            }
        }
        __syncthreads();   // cs (and xn, first iter) ready

        if (ch == 0) {
#pragma unroll
            for (int i = 0; i < 8; ++i) xnr[i] = xn[pl0 + i];
        }

#pragma unroll
        for (int i = 0; i < 8; ++i)
#pragma unroll
            for (int j = 0; j < 16; ++j) acc[i][j] = 0.f;

#pragma unroll 2
        for (int d = 0; d < DIM; ++d) {
            const float* xr = xs + d * BPIX + pl0;
            const float* cr = cs + d * CHUNK + kb + wx4;
            float4 xlo = *reinterpret_cast<const float4*>(xr);
            float4 xhi = *reinterpret_cast<const float4*>(xr + 4);
            float4 cfA = *reinterpret_cast<const float4*>(cr);        // j=0
            float4 cfB = *reinterpret_cast<const float4*>(cr + 32);   // j=1
            float4 cfC = *reinterpret_cast<const float4*>(cr + 64);   // j=2
            float4 cfD = *reinterpret_cast<const float4*>(cr + 96);   // j=3
#define ROW(i, xi) \
            acc[i][ 0]=fmaf(xi,cfA.x,acc[i][ 0]); acc[i][ 1]=fmaf(xi,cfA.y,acc[i][ 1]); \
            acc[i][ 2]=fmaf(xi,cfA.z,acc[i][ 2]); acc[i][ 3]=fmaf(xi,cfA.w,acc[i][ 3]); \
            acc[i][ 4]=fmaf(xi,cfB.x,acc[i][ 4]); acc[i][ 5]=fmaf(xi,cfB.y,acc[i][ 5]); \
            acc[i][ 6]=fmaf(xi,cfB.z,acc[i][ 6]); acc[i][ 7]=fmaf(xi,cfB.w,acc[i][ 7]); \
            acc[i][ 8]=fmaf(xi,cfC.x,acc[i][ 8]); acc[i][ 9]=fmaf(xi,cfC.y,acc[i][ 9]); \
            acc[i][10]=fmaf(xi,cfC.z,acc[i][10]); acc[i][11]=fmaf(xi,cfC.w,acc[i][11]); \
            acc[i][12]=fmaf(xi,cfD.x,acc[i][12]); acc[i][13]=fmaf(xi,cfD.y,acc[i][13]); \
            acc[i][14]=fmaf(xi,cfD.z,acc[i][14]); acc[i][15]=fmaf(xi,cfD.w,acc[i][15]);
            ROW(0, xlo.x) ROW(1, xlo.y) ROW(2, xlo.z) ROW(3, xlo.w)
            ROW(4, xhi.x) ROW(5, xhi.y) ROW(6, xhi.z) ROW(7, xhi.w)
#undef ROW
        }

        // epilogue: reference rounding (xn - 2*dot) + c2 (proven exact r2-r8);
        // per-thread (j,e) ascending == global k ascending -> first-min ties.
        int kgc = ks * 512 + ch * 256 + kb + wx4;
#pragma unroll
        for (int j = 0; j < 4; ++j) {
            float4 c2v = *reinterpret_cast<const float4*>(&c2[kgc + j * 32]);
#pragma unroll
            for (int i = 0; i < 8; ++i) {
                float d0 = (xnr[i] - 2.0f * acc[i][j * 4 + 0]) + c2v.x;
                float d1 = (xnr[i] - 2.0f * acc[i][j * 4 + 1]) + c2v.y;
                float d2 = (xnr[i] - 2.0f * acc[i][j * 4 + 2]) + c2v.z;
                float d3 = (xnr[i] - 2.0f * acc[i][j * 4 + 3]) + c2v.w;
                int k = kgc + j * 32;
                if (d0 < bv[i]) { bv[i] = d0; bk[i] = k + 0; }
                if (d1 < bv[i]) { bv[i] = d1; bk[i] = k + 1; }
                if (d2 < bv[i]) { bv[i] = d2; bk[i] = k + 2; }
                if (d3 < bv[i]) { bv[i] = d3; bk[i] = k + 3; }
            }
        }
        __syncthreads();   // protect cs before chunk-1 overwrite
    }

    // ---- cross-wx shuffle reduce; scattered k -> lex (val,k) = first-min
#pragma unroll
    for (int i = 0; i < 8; ++i) {
#pragma unroll
        for (int off = 1; off <= 4; off <<= 1) {
            float ov = __shfl_xor(bv[i], off);
            int   ok = __shfl_xor(bk[i], off);
            if (ov < bv[i] || (ov == bv[i] && ok < bk[i])) { bv[i] = ov; bk[i] = ok; }
        }
    }
    if (wx == 0) {
#pragma unroll
        for (int i = 0; i < 8; ++i)
            red[wc][pl0 + i] = make_float2(bv[i], __int_as_float(bk[i]));
    }
    __syncthreads();

    // ---- merge the two code-halves (interleaved k -> lex), emit partial
    if (t < BPIX) {
        float2 r0 = red[0][t], r1 = red[1][t];
        int k0i = __float_as_int(r0.y), k1i = __float_as_int(r1.y);
        float fv = r0.x; int fk = k0i;
        if (r1.x < fv || (r1.x == fv && k1i < fk)) { fv = r1.x; fk = k1i; }
        part[(size_t)ks * N_PIX + p_base + t] = make_float2(fv, __int_as_float(fk));
    }
}

// Merge the 2 K-split partials (split 0 holds smaller k: strict < = first-min),
// store idx, write quantized [B, D, H, W]. grid = 256 x 128.
__global__ __launch_bounds__(128) void reduce_quant(const float* __restrict__ cb,
                                                    const float2* __restrict__ part,
                                                    int* __restrict__ idx,
                                                    float* __restrict__ quant) {
    int n = blockIdx.x * 128 + threadIdx.x;
    float2 r0 = part[n];
    float2 r1 = part[(size_t)N_PIX + n];
    float best = r0.x; int bi = __float_as_int(r0.y);
    if (r1.x < best) { best = r1.x; bi = __float_as_int(r1.y); }
    idx[n] = bi;

    int bb = n >> 10;
    int hw = n & 1023;
    const float4* crow = reinterpret_cast<const float4*>(cb + (size_t)bi * DIM);
    float* qb = quant + (size_t)bb * (DIM * 1024) + hw;
#pragma unroll
    for (int dq = 0; dq < 16; ++dq) {
        float4 cv = crow[dq];            // L2-resident gather
        qb[(size_t)(dq * 4 + 0) << 10] = cv.x;   // consecutive hw lanes -> coalesced
        qb[(size_t)(dq * 4 + 1) << 10] = cv.y;
        qb[(size_t)(dq * 4 + 2) << 10] = cv.z;
        qb[(size_t)(dq * 4 + 3) << 10] = cv.w;
    }
}

// Streaming one-hot writer: flat float4 index e covers enc[n][j0..j0+3],
// n = e>>8, j0 = (e&255)*4. grid-stride, 2048 blocks.
__global__ __launch_bounds__(256) void enc_write(const int* __restrict__ idx,
                                                 float* __restrict__ enc) {
    const int TOT = (N_PIX / 4) * K_CODES;   // 8388608 float4s
    int tid = blockIdx.x * 256 + threadIdx.x;
    float4* enc4 = reinterpret_cast<float4*>(enc);
    for (int e = tid; e < TOT; e += 2048 * 256) {
        int n  = e >> 8;
        int j0 = (e & 255) << 2;
        int ir = idx[n];                 // row-uniform -> L1/L2 broadcast
        float4 v;
        v.x = (ir == j0 + 0) ? 1.0f : 0.0f;
        v.y = (ir == j0 + 1) ? 1.0f : 0.0f;
        v.z = (ir == j0 + 2) ? 1.0f : 0.0f;
        v.w = (ir == j0 + 3) ? 1.0f : 0.0f;
        enc4[e] = v;
    }
}

extern "C" void kernel_launch(void* const* d_in, const int* in_sizes, int n_in,
                              void* d_out, int out_size, void* d_ws, size_t ws_size,
                              hipStream_t stream) {
    const float* x  = (const float*)d_in[0];
    const float* cb = (const float*)d_in[1];

    float*  c2   = (float*)d_ws;
    float2* part = (float2*)((char*)d_ws + 4096);
    int*    idx  = (int*)((char*)d_ws + 4096 + (size_t)NSPLIT * N_PIX * 8);

    float* enc   = (float*)d_out;                           // [32768, 1024]
    float* quant = (float*)d_out + (size_t)N_PIX * K_CODES; // [32, 64, 32, 32]

    c2_kernel<<<K_CODES / 256, 256, 0, stream>>>(cb, c2);
    argmin_tile<<<(N_PIX / BPIX) * NSPLIT, 512, 0, stream>>>(x, cb, c2, part);
    reduce_quant<<<N_PIX / 128, 128, 0, stream>>>(cb, part, idx, quant);
    enc_write<<<2048, 256, 0, stream>>>(idx, enc);
}

// Round 10
// 228.630 us; speedup vs baseline: 1.0873x; 1.0873x over previous
//
#include <hip/hip_runtime.h>

#define N_PIX    32768
#define DIM      64
#define K_CODES  1024
#define BPIX     128          // pixels per block
#define CHUNK    128          // codes per block (single chunk, K split 8 ways)
#define NSPLIT   8

// ws layout: [0,4096) c2[1024] ; [4096, +2MiB) part float2[NSPLIT][N_PIX] ;
//            [4096+2MiB, +128KiB) idx[N_PIX]

__global__ __launch_bounds__(256) void c2_kernel(const float* __restrict__ cb,
                                                 float* __restrict__ c2) {
    int k = blockIdx.x * 256 + threadIdx.x;
    if (k >= K_CODES) return;
    const float* row = cb + k * DIM;
    float a0 = 0.f, a1 = 0.f, a2 = 0.f, a3 = 0.f;
#pragma unroll
    for (int d = 0; d < DIM; d += 4) {
        a0 = fmaf(row[d + 0], row[d + 0], a0);
        a1 = fmaf(row[d + 1], row[d + 1], a1);
        a2 = fmaf(row[d + 2], row[d + 2], a2);
        a3 = fmaf(row[d + 3], row[d + 3], a3);
    }
    c2[k] = (a0 + a1) + (a2 + a3);
}

// 256 threads = 4 waves (2 prow x 2 kcol); wave = 8wy x 8wx; thread tile 8x8
// (64 acc — the proven allocatable max, r7/r9 showed 128 acc -> AGPR split).
// Block tile 128 pix x 128 codes, ONE chunk per block; K split over 8 blocks.
// LDS 67KB -> 2 blocks/CU: independent blocks decouple barrier stalls that
// capped round 8 at ~70us (DS floor 40us). launch_bounds(256,4): VGPR cap 128.
__global__ __launch_bounds__(256, 4) void argmin_tile(const float* __restrict__ x,
                                                      const float* __restrict__ cb,
                                                      const float* __restrict__ c2,
                                                      float2* __restrict__ part) {
    __shared__ alignas(16) float xs[DIM * BPIX];     // 32 KB [d][p]
    __shared__ alignas(16) float cs[DIM * CHUNK];    // 32 KB [d][k]
    __shared__ float  xn[BPIX];                      // 512 B
    __shared__ float2 red[2][BPIX];                  // 2 KB

    const int t      = threadIdx.x;
    const int blk    = blockIdx.x;
    const int split  = blk & 7;           // consecutive blocks share the x slab
    const int pixblk = blk >> 3;          // 0..255
    const int p_base = pixblk * BPIX;
    const int bb     = p_base >> 10;
    const int hw0    = p_base & 1023;     // 128-aligned: block stays in batch
    const int k_base = split * CHUNK;

    const float4* x4  = reinterpret_cast<const float4*>(x);
    const float4* cb4 = reinterpret_cast<const float4*>(cb);

    // ---- stage xs[d][p]: rows contiguous in x -> coalesced float4 (8/thread)
#pragma unroll
    for (int i = 0; i < 8; ++i) {
        int fidx = i * 256 + t;           // 0..2047
        int d = fidx >> 5, p4 = fidx & 31;
        reinterpret_cast<float4*>(xs)[d * 32 + p4] =
            x4[(size_t)bb * 16384 + (size_t)d * 256 + (hw0 >> 2) + p4];
    }

    // ---- stage cs[d][k] (transpose of cb[k][d]) via 2 reg passes of 4 float4.
    // k lane-fast -> staging writes hit distinct banks (2-way alias, free).
#pragma unroll
    for (int pass = 0; pass < 2; ++pass) {
        float4 creg[4];
#pragma unroll
        for (int i = 0; i < 4; ++i) {
            int fidx = pass * 1024 + i * 256 + t;   // 0..2047
            int k = fidx & 127, dq = fidx >> 7;
            creg[i] = cb4[(size_t)(k_base + k) * 16 + dq];
        }
#pragma unroll
        for (int i = 0; i < 4; ++i) {
            int fidx = pass * 1024 + i * 256 + t;
            int k = fidx & 127, dq = fidx >> 7;
            cs[(4 * dq + 0) * CHUNK + k] = creg[i].x;
            cs[(4 * dq + 1) * CHUNK + k] = creg[i].y;
            cs[(4 * dq + 2) * CHUNK + k] = creg[i].z;
            cs[(4 * dq + 3) * CHUNK + k] = creg[i].w;
        }
    }
    __syncthreads();

    // ---- xn: EXACT tree of passing rounds (s[d%4] ascending, (s0+s1)+(s2+s3))
    if (t < BPIX) {
        float s0 = 0.f, s1 = 0.f, s2 = 0.f, s3 = 0.f;
#pragma unroll
        for (int d = 0; d < DIM; d += 4) {
            float v0 = xs[(d + 0) * BPIX + t];
            float v1 = xs[(d + 1) * BPIX + t];
            float v2 = xs[(d + 2) * BPIX + t];
            float v3 = xs[(d + 3) * BPIX + t];
            s0 = fmaf(v0, v0, s0);
            s1 = fmaf(v1, v1, s1);
            s2 = fmaf(v2, v2, s2);
            s3 = fmaf(v3, v3, s3);
        }
        xn[t] = (s0 + s1) + (s2 + s3);
    }

    // ---- wave decomposition: 4 waves = 2 prow x 2 kcol
    const int lane = t & 63, w = t >> 6;
    const int wy = lane >> 3, wx = lane & 7;
    const int wr = w >> 1,    wc = w & 1;
    const int pl0 = wr * 64 + wy * 8;     // 0..120
    const int kl0 = wc * 64 + wx * 8;     // 0..120

    float acc[8][8];
#pragma unroll
    for (int i = 0; i < 8; ++i)
#pragma unroll
        for (int j = 0; j < 8; ++j) acc[i][j] = 0.f;

#pragma unroll 2
    for (int d = 0; d < DIM; ++d) {
        const float* xr = xs + d * BPIX + pl0;
        const float* cr = cs + d * CHUNK + kl0;
        float4 xlo = *reinterpret_cast<const float4*>(xr);
        float4 xhi = *reinterpret_cast<const float4*>(xr + 4);
        float4 clo = *reinterpret_cast<const float4*>(cr);
        float4 chi = *reinterpret_cast<const float4*>(cr + 4);
#define ROW(i, xi) \
        acc[i][0] = fmaf(xi, clo.x, acc[i][0]); \
        acc[i][1] = fmaf(xi, clo.y, acc[i][1]); \
        acc[i][2] = fmaf(xi, clo.z, acc[i][2]); \
        acc[i][3] = fmaf(xi, clo.w, acc[i][3]); \
        acc[i][4] = fmaf(xi, chi.x, acc[i][4]); \
        acc[i][5] = fmaf(xi, chi.y, acc[i][5]); \
        acc[i][6] = fmaf(xi, chi.z, acc[i][6]); \
        acc[i][7] = fmaf(xi, chi.w, acc[i][7]);
        ROW(0, xlo.x) ROW(1, xlo.y) ROW(2, xlo.z) ROW(3, xlo.w)
        ROW(4, xhi.x) ROW(5, xhi.y) ROW(6, xhi.z) ROW(7, xhi.w)
#undef ROW
    }
    __syncthreads();   // xn ready (also keeps cs live until here)

    // ---- epilogue: reference rounding (xn - 2*dot) + c2 (proven exact r2-r9);
    // j ascending == k ascending within thread -> first-min ties.
    float bv[8]; int bk[8];
    {
        float4 c2lo = *reinterpret_cast<const float4*>(&c2[k_base + kl0]);
        float4 c2hi = *reinterpret_cast<const float4*>(&c2[k_base + kl0 + 4]);
        float c2a[8] = {c2lo.x, c2lo.y, c2lo.z, c2lo.w,
                        c2hi.x, c2hi.y, c2hi.z, c2hi.w};
#pragma unroll
        for (int i = 0; i < 8; ++i) {
            float xni = xn[pl0 + i];
            bv[i] = 1e30f; bk[i] = 0;
#pragma unroll
            for (int j = 0; j < 8; ++j) {
                float dist = (xni - 2.0f * acc[i][j]) + c2a[j];
                if (dist < bv[i]) { bv[i] = dist; bk[i] = k_base + kl0 + j; }
            }
        }
    }

    // ---- cross-wx shuffle reduce: lex (val,k) == global first-min
#pragma unroll
    for (int i = 0; i < 8; ++i) {
#pragma unroll
        for (int off = 1; off <= 4; off <<= 1) {
            float ov = __shfl_xor(bv[i], off);
            int   ok = __shfl_xor(bk[i], off);
            if (ov < bv[i] || (ov == bv[i] && ok < bk[i])) { bv[i] = ov; bk[i] = ok; }
        }
    }
    if (wx == 0) {
#pragma unroll
        for (int i = 0; i < 8; ++i)
            red[wc][pl0 + i] = make_float2(bv[i], __int_as_float(bk[i]));
    }
    __syncthreads();

    // ---- merge the two code-halves (wc0 k < wc1 k: lex), emit split partial
    if (t < BPIX) {
        float2 r0 = red[0][t], r1 = red[1][t];
        int k0i = __float_as_int(r0.y), k1i = __float_as_int(r1.y);
        float fv = r0.x; int fk = k0i;
        if (r1.x < fv || (r1.x == fv && k1i < fk)) { fv = r1.x; fk = k1i; }
        part[(size_t)split * N_PIX + p_base + t] = make_float2(fv, __int_as_float(fk));
    }
}

// Reduce the 8 split partials per pixel (ascending split = ascending k, strict
// < = first-min), store idx, write quantized [B, D, H, W]. grid = 256 x 128.
__global__ __launch_bounds__(128) void reduce_quant(const float* __restrict__ cb,
                                                    const float2* __restrict__ part,
                                                    int* __restrict__ idx,
                                                    float* __restrict__ quant) {
    int n = blockIdx.x * 128 + threadIdx.x;
    float best = 1e30f;
    int   bi = 0;
#pragma unroll
    for (int c = 0; c < NSPLIT; ++c) {
        float2 r = part[(size_t)c * N_PIX + n];
        if (r.x < best) { best = r.x; bi = __float_as_int(r.y); }
    }
    idx[n] = bi;

    int bb = n >> 10;
    int hw = n & 1023;
    const float4* crow = reinterpret_cast<const float4*>(cb + (size_t)bi * DIM);
    float* qb = quant + (size_t)bb * (DIM * 1024) + hw;
#pragma unroll
    for (int dq = 0; dq < 16; ++dq) {
        float4 cv = crow[dq];            // L2-resident gather
        qb[(size_t)(dq * 4 + 0) << 10] = cv.x;   // consecutive hw lanes -> coalesced
        qb[(size_t)(dq * 4 + 1) << 10] = cv.y;
        qb[(size_t)(dq * 4 + 2) << 10] = cv.z;
        qb[(size_t)(dq * 4 + 3) << 10] = cv.w;
    }
}

// Streaming one-hot writer: flat float4 index e covers enc[n][j0..j0+3],
// n = e>>8, j0 = (e&255)*4. grid-stride, 2048 blocks.
__global__ __launch_bounds__(256) void enc_write(const int* __restrict__ idx,
                                                 float* __restrict__ enc) {
    const int TOT = (N_PIX / 4) * K_CODES;   // 8388608 float4s
    int tid = blockIdx.x * 256 + threadIdx.x;
    float4* enc4 = reinterpret_cast<float4*>(enc);
    for (int e = tid; e < TOT; e += 2048 * 256) {
        int n  = e >> 8;
        int j0 = (e & 255) << 2;
        int ir = idx[n];                 // row-uniform -> L1/L2 broadcast
        float4 v;
        v.x = (ir == j0 + 0) ? 1.0f : 0.0f;
        v.y = (ir == j0 + 1) ? 1.0f : 0.0f;
        v.z = (ir == j0 + 2) ? 1.0f : 0.0f;
        v.w = (ir == j0 + 3) ? 1.0f : 0.0f;
        enc4[e] = v;
    }
}

extern "C" void kernel_launch(void* const* d_in, const int* in_sizes, int n_in,
                              void* d_out, int out_size, void* d_ws, size_t ws_size,
                              hipStream_t stream) {
    const float* x  = (const float*)d_in[0];
    const float* cb = (const float*)d_in[1];

    float*  c2   = (float*)d_ws;
    float2* part = (float2*)((char*)d_ws + 4096);
    int*    idx  = (int*)((char*)d_ws + 4096 + (size_t)NSPLIT * N_PIX * 8);

    float* enc   = (float*)d_out;                           // [32768, 1024]
    float* quant = (float*)d_out + (size_t)N_PIX * K_CODES; // [32, 64, 32, 32]

    c2_kernel<<<K_CODES / 256, 256, 0, stream>>>(cb, c2);
    argmin_tile<<<(N_PIX / BPIX) * NSPLIT, 256, 0, stream>>>(x, cb, c2, part);
    reduce_quant<<<N_PIX / 128, 128, 0, stream>>>(cb, part, idx, quant);
    enc_write<<<2048, 256, 0, stream>>>(idx, enc);
}

// Round 11
// 227.932 us; speedup vs baseline: 1.0906x; 1.0031x over previous
//
#include <hip/hip_runtime.h>

#define N_PIX    32768
#define DIM      64
#define K_CODES  1024
#define BPIX     128          // pixels per block
#define CHUNK    128          // codes per block (single chunk, K split 8 ways)
#define NSPLIT   8

// ws layout: [0,4096) c2[1024] ; [4096, +2MiB) part float2[NSPLIT][N_PIX] ;
//            [4096+2MiB, +128KiB) idx[N_PIX]

__global__ __launch_bounds__(256) void c2_kernel(const float* __restrict__ cb,
                                                 float* __restrict__ c2) {
    int k = blockIdx.x * 256 + threadIdx.x;
    if (k >= K_CODES) return;
    const float* row = cb + k * DIM;
    float a0 = 0.f, a1 = 0.f, a2 = 0.f, a3 = 0.f;
#pragma unroll
    for (int d = 0; d < DIM; d += 4) {
        a0 = fmaf(row[d + 0], row[d + 0], a0);
        a1 = fmaf(row[d + 1], row[d + 1], a1);
        a2 = fmaf(row[d + 2], row[d + 2], a2);
        a3 = fmaf(row[d + 3], row[d + 3], a3);
    }
    c2[k] = (a0 + a1) + (a2 + a3);
}

// 256 threads = 4 waves (2 prow x 2 kcol); wave = 8wy x 8wx; thread tile 8x8.
// c-codes SCATTERED: k = wc*64 + g*32 + wx*4 (g=0,1) so each c-b128 phase
// covers banks 4wx..4wx+3 = all 32 banks once (round 10's contiguous wx*8
// layout cost 1.15e7 conflict cycles = +19us; round 9's scatter measured ~0).
// x-reads are wy-broadcast (conflict-free). 2 blocks/CU (LDS 67KB), K split 8.
__global__ __launch_bounds__(256, 4) void argmin_tile(const float* __restrict__ x,
                                                      const float* __restrict__ cb,
                                                      const float* __restrict__ c2,
                                                      float2* __restrict__ part) {
    __shared__ alignas(16) float xs[DIM * BPIX];     // 32 KB [d][p]
    __shared__ alignas(16) float cs[DIM * CHUNK];    // 32 KB [d][k]
    __shared__ float  xn[BPIX];                      // 512 B
    __shared__ float2 red[2][BPIX];                  // 2 KB

    const int t      = threadIdx.x;
    const int blk    = blockIdx.x;
    const int split  = blk & 7;           // consecutive blocks share the x slab
    const int pixblk = blk >> 3;          // 0..255
    const int p_base = pixblk * BPIX;
    const int bb     = p_base >> 10;
    const int hw0    = p_base & 1023;     // 128-aligned: block stays in batch
    const int k_base = split * CHUNK;

    const float4* x4  = reinterpret_cast<const float4*>(x);
    const float4* cb4 = reinterpret_cast<const float4*>(cb);

    // ---- stage xs[d][p]: rows contiguous in x -> coalesced float4 (8/thread)
#pragma unroll
    for (int i = 0; i < 8; ++i) {
        int fidx = i * 256 + t;           // 0..2047
        int d = fidx >> 5, p4 = fidx & 31;
        reinterpret_cast<float4*>(xs)[d * 32 + p4] =
            x4[(size_t)bb * 16384 + (size_t)d * 256 + (hw0 >> 2) + p4];
    }

    // ---- stage cs[d][k] (transpose of cb[k][d]) via 2 reg passes of 4 float4.
    // k lane-fast -> staging writes hit distinct banks (2-way alias, free).
#pragma unroll
    for (int pass = 0; pass < 2; ++pass) {
        float4 creg[4];
#pragma unroll
        for (int i = 0; i < 4; ++i) {
            int fidx = pass * 1024 + i * 256 + t;   // 0..2047
            int k = fidx & 127, dq = fidx >> 7;
            creg[i] = cb4[(size_t)(k_base + k) * 16 + dq];
        }
#pragma unroll
        for (int i = 0; i < 4; ++i) {
            int fidx = pass * 1024 + i * 256 + t;
            int k = fidx & 127, dq = fidx >> 7;
            cs[(4 * dq + 0) * CHUNK + k] = creg[i].x;
            cs[(4 * dq + 1) * CHUNK + k] = creg[i].y;
            cs[(4 * dq + 2) * CHUNK + k] = creg[i].z;
            cs[(4 * dq + 3) * CHUNK + k] = creg[i].w;
        }
    }
    __syncthreads();

    // ---- xn: EXACT tree of passing rounds (s[d%4] ascending, (s0+s1)+(s2+s3))
    if (t < BPIX) {
        float s0 = 0.f, s1 = 0.f, s2 = 0.f, s3 = 0.f;
#pragma unroll
        for (int d = 0; d < DIM; d += 4) {
            float v0 = xs[(d + 0) * BPIX + t];
            float v1 = xs[(d + 1) * BPIX + t];
            float v2 = xs[(d + 2) * BPIX + t];
            float v3 = xs[(d + 3) * BPIX + t];
            s0 = fmaf(v0, v0, s0);
            s1 = fmaf(v1, v1, s1);
            s2 = fmaf(v2, v2, s2);
            s3 = fmaf(v3, v3, s3);
        }
        xn[t] = (s0 + s1) + (s2 + s3);
    }

    // ---- wave decomposition: 4 waves = 2 prow x 2 kcol
    const int lane = t & 63, w = t >> 6;
    const int wy = lane >> 3, wx = lane & 7;
    const int wr = w >> 1,    wc = w & 1;
    const int pl0 = wr * 64 + wy * 8;     // 0..120
    const int kc0 = wc * 64 + wx * 4;     // scattered base: group g at +g*32

    float acc[8][8];                      // j = g*4 + e
#pragma unroll
    for (int i = 0; i < 8; ++i)
#pragma unroll
        for (int j = 0; j < 8; ++j) acc[i][j] = 0.f;

#pragma unroll 2
    for (int d = 0; d < DIM; ++d) {
        const float* xr = xs + d * BPIX + pl0;
        const float* cr = cs + d * CHUNK + kc0;
        float4 xlo = *reinterpret_cast<const float4*>(xr);
        float4 xhi = *reinterpret_cast<const float4*>(xr + 4);
        float4 cfA = *reinterpret_cast<const float4*>(cr);        // g=0
        float4 cfB = *reinterpret_cast<const float4*>(cr + 32);   // g=1
#define ROW(i, xi) \
        acc[i][0] = fmaf(xi, cfA.x, acc[i][0]); \
        acc[i][1] = fmaf(xi, cfA.y, acc[i][1]); \
        acc[i][2] = fmaf(xi, cfA.z, acc[i][2]); \
        acc[i][3] = fmaf(xi, cfA.w, acc[i][3]); \
        acc[i][4] = fmaf(xi, cfB.x, acc[i][4]); \
        acc[i][5] = fmaf(xi, cfB.y, acc[i][5]); \
        acc[i][6] = fmaf(xi, cfB.z, acc[i][6]); \
        acc[i][7] = fmaf(xi, cfB.w, acc[i][7]);
        ROW(0, xlo.x) ROW(1, xlo.y) ROW(2, xlo.z) ROW(3, xlo.w)
        ROW(4, xhi.x) ROW(5, xhi.y) ROW(6, xhi.z) ROW(7, xhi.w)
#undef ROW
    }
    __syncthreads();   // xn ready (also keeps cs live until here)

    // ---- epilogue: reference rounding (xn - 2*dot) + c2 (proven exact
    // r2-r10); within-thread (g,e) ascending == k ascending -> first-min.
    float bv[8]; int bk[8];
    {
        float4 c2A = *reinterpret_cast<const float4*>(&c2[k_base + kc0]);
        float4 c2B = *reinterpret_cast<const float4*>(&c2[k_base + kc0 + 32]);
        float c2a[8] = {c2A.x, c2A.y, c2A.z, c2A.w,
                        c2B.x, c2B.y, c2B.z, c2B.w};
#pragma unroll
        for (int i = 0; i < 8; ++i) {
            float xni = xn[pl0 + i];
            bv[i] = 1e30f; bk[i] = 0;
#pragma unroll
            for (int j = 0; j < 8; ++j) {
                float dist = (xni - 2.0f * acc[i][j]) + c2a[j];
                int   k    = k_base + kc0 + (j >> 2) * 32 + (j & 3);
                if (dist < bv[i]) { bv[i] = dist; bk[i] = k; }
            }
        }
    }

    // ---- cross-wx shuffle reduce: lex (val,k) == global first-min
#pragma unroll
    for (int i = 0; i < 8; ++i) {
#pragma unroll
        for (int off = 1; off <= 4; off <<= 1) {
            float ov = __shfl_xor(bv[i], off);
            int   ok = __shfl_xor(bk[i], off);
            if (ov < bv[i] || (ov == bv[i] && ok < bk[i])) { bv[i] = ov; bk[i] = ok; }
        }
    }
    if (wx == 0) {
#pragma unroll
        for (int i = 0; i < 8; ++i)
            red[wc][pl0 + i] = make_float2(bv[i], __int_as_float(bk[i]));
    }
    __syncthreads();

    // ---- merge the two code-halves (lex (val,k)), emit split partial
    if (t < BPIX) {
        float2 r0 = red[0][t], r1 = red[1][t];
        int k0i = __float_as_int(r0.y), k1i = __float_as_int(r1.y);
        float fv = r0.x; int fk = k0i;
        if (r1.x < fv || (r1.x == fv && k1i < fk)) { fv = r1.x; fk = k1i; }
        part[(size_t)split * N_PIX + p_base + t] = make_float2(fv, __int_as_float(fk));
    }
}

// Reduce the 8 split partials per pixel (ascending split = ascending k, strict
// < = first-min), store idx, write quantized [B, D, H, W]. grid = 256 x 128.
__global__ __launch_bounds__(128) void reduce_quant(const float* __restrict__ cb,
                                                    const float2* __restrict__ part,
                                                    int* __restrict__ idx,
                                                    float* __restrict__ quant) {
    int n = blockIdx.x * 128 + threadIdx.x;
    float best = 1e30f;
    int   bi = 0;
#pragma unroll
    for (int c = 0; c < NSPLIT; ++c) {
        float2 r = part[(size_t)c * N_PIX + n];
        if (r.x < best) { best = r.x; bi = __float_as_int(r.y); }
    }
    idx[n] = bi;

    int bb = n >> 10;
    int hw = n & 1023;
    const float4* crow = reinterpret_cast<const float4*>(cb + (size_t)bi * DIM);
    float* qb = quant + (size_t)bb * (DIM * 1024) + hw;
#pragma unroll
    for (int dq = 0; dq < 16; ++dq) {
        float4 cv = crow[dq];            // L2-resident gather
        qb[(size_t)(dq * 4 + 0) << 10] = cv.x;   // consecutive hw lanes -> coalesced
        qb[(size_t)(dq * 4 + 1) << 10] = cv.y;
        qb[(size_t)(dq * 4 + 2) << 10] = cv.z;
        qb[(size_t)(dq * 4 + 3) << 10] = cv.w;
    }
}

// Streaming one-hot writer: flat float4 index e covers enc[n][j0..j0+3],
// n = e>>8, j0 = (e&255)*4. grid-stride, 2048 blocks.
__global__ __launch_bounds__(256) void enc_write(const int* __restrict__ idx,
                                                 float* __restrict__ enc) {
    const int TOT = (N_PIX / 4) * K_CODES;   // 8388608 float4s
    int tid = blockIdx.x * 256 + threadIdx.x;
    float4* enc4 = reinterpret_cast<float4*>(enc);
    for (int e = tid; e < TOT; e += 2048 * 256) {
        int n  = e >> 8;
        int j0 = (e & 255) << 2;
        int ir = idx[n];                 // row-uniform -> L1/L2 broadcast
        float4 v;
        v.x = (ir == j0 + 0) ? 1.0f : 0.0f;
        v.y = (ir == j0 + 1) ? 1.0f : 0.0f;
        v.z = (ir == j0 + 2) ? 1.0f : 0.0f;
        v.w = (ir == j0 + 3) ? 1.0f : 0.0f;
        enc4[e] = v;
    }
}

extern "C" void kernel_launch(void* const* d_in, const int* in_sizes, int n_in,
                              void* d_out, int out_size, void* d_ws, size_t ws_size,
                              hipStream_t stream) {
    const float* x  = (const float*)d_in[0];
    const float* cb = (const float*)d_in[1];

    float*  c2   = (float*)d_ws;
    float2* part = (float2*)((char*)d_ws + 4096);
    int*    idx  = (int*)((char*)d_ws + 4096 + (size_t)NSPLIT * N_PIX * 8);

    float* enc   = (float*)d_out;                           // [32768, 1024]
    float* quant = (float*)d_out + (size_t)N_PIX * K_CODES; // [32, 64, 32, 32]

    c2_kernel<<<K_CODES / 256, 256, 0, stream>>>(cb, c2);
    argmin_tile<<<(N_PIX / BPIX) * NSPLIT, 256, 0, stream>>>(x, cb, c2, part);
    reduce_quant<<<N_PIX / 128, 128, 0, stream>>>(cb, part, idx, quant);
    enc_write<<<2048, 256, 0, stream>>>(idx, enc);
}

// Round 13
// 207.954 us; speedup vs baseline: 1.1954x; 1.0961x over previous
//
#include <hip/hip_runtime.h>

#define N_PIX    32768
#define DIM      64
#define K_CODES  1024
#define BPIX     128          // pixels per block
#define CHUNK    256          // codes per LDS chunk
#define NCHUNK   4            // full K per block: no splits, no partials

// ws layout: [0,4096) c2[1024] ; [4096, +128KiB) idx[N_PIX]

__global__ __launch_bounds__(256) void c2_kernel(const float* __restrict__ cb,
                                                 float* __restrict__ c2) {
    int k = blockIdx.x * 256 + threadIdx.x;
    if (k >= K_CODES) return;
    const float* row = cb + k * DIM;
    float a0 = 0.f, a1 = 0.f, a2 = 0.f, a3 = 0.f;
#pragma unroll
    for (int d = 0; d < DIM; d += 4) {
        a0 = fmaf(row[d + 0], row[d + 0], a0);
        a1 = fmaf(row[d + 1], row[d + 1], a1);
        a2 = fmaf(row[d + 2], row[d + 2], a2);
        a3 = fmaf(row[d + 3], row[d + 3], a3);
    }
    c2[k] = (a0 + a1) + (a2 + a3);
}

// 512 threads = 8 waves (2 prow x 4 kcol); wave = 8wy x 8wx; thread tile 8x8
// (64 acc = proven allocatable max; r7/r9's 128-acc triggered AGPR splitting).
// Block = 128 pix x FULL 1024 codes as 4 chunks of 256 (x staged ONCE — r11's
// NSPLIT=8 redundancy cost ~17us/CU). c-codes scattered k = wc*64+g*32+wx*4:
// each c-b128 phase hits banks 4wx..4wx+3 = all 32, conflict-free (r11: 1.6e4
// vs r10's contiguous 1.15e7). Reg-prefetch next chunk hides global latency.
// grid = 256 = 1 block/CU; LDS ~103K; launch_bounds(512,2) -> VGPR cap 256.
__global__ __launch_bounds__(512, 2) void argmin_tile(const float* __restrict__ x,
                                                      const float* __restrict__ cb,
                                                      const float* __restrict__ c2,
                                                      int* __restrict__ idx,
                                                      float* __restrict__ quant) {
    __shared__ alignas(16) float xs[DIM * BPIX];     // 32 KB [d][p]
    __shared__ alignas(16) float cs[DIM * CHUNK];    // 64 KB [d][k]
    __shared__ float  xn[BPIX];                      // 512 B
    __shared__ float2 red[4][BPIX];                  // 4 KB
    __shared__ int    sidx[BPIX];                    // 512 B

    const int t      = threadIdx.x;
    const int blk    = blockIdx.x;                   // 0..255 = pixblk
    const int p_base = blk * BPIX;
    const int bb     = p_base >> 10;
    const int hw0    = p_base & 1023;                // 128-aligned: stays in batch

    const float4* x4  = reinterpret_cast<const float4*>(x);
    const float4* cb4 = reinterpret_cast<const float4*>(cb);

    // ---- stage xs[d][p]: rows contiguous in x -> coalesced float4 (4/thread)
#pragma unroll
    for (int i = 0; i < 4; ++i) {
        int fidx = i * 512 + t;           // 0..2047
        int d = fidx >> 5, p4 = fidx & 31;
        reinterpret_cast<float4*>(xs)[d * 32 + p4] =
            x4[(size_t)bb * 16384 + (size_t)d * 256 + (hw0 >> 2) + p4];
    }

    // ---- prefetch chunk-0 codebook tile into regs (k lane-fast: LDS-write
    // conflict-free; global 256B-strided but cb is 256KB L2-resident)
    float4 creg[8];
#pragma unroll
    for (int i = 0; i < 8; ++i) {
        int fidx = i * 512 + t;           // 0..4095
        int k = fidx & 255, dq = fidx >> 8;
        creg[i] = cb4[(size_t)k * 16 + dq];
    }
    __syncthreads();                      // xs ready

    // ---- xn: EXACT tree of passing rounds (s[d%4] ascending, (s0+s1)+(s2+s3))
    if (t < BPIX) {
        float s0 = 0.f, s1 = 0.f, s2 = 0.f, s3 = 0.f;
#pragma unroll
        for (int d = 0; d < DIM; d += 4) {
            float v0 = xs[(d + 0) * BPIX + t];
            float v1 = xs[(d + 1) * BPIX + t];
            float v2 = xs[(d + 2) * BPIX + t];
            float v3 = xs[(d + 3) * BPIX + t];
            s0 = fmaf(v0, v0, s0);
            s1 = fmaf(v1, v1, s1);
            s2 = fmaf(v2, v2, s2);
            s3 = fmaf(v3, v3, s3);
        }
        xn[t] = (s0 + s1) + (s2 + s3);
    }

    // ---- wave decomposition: 8 waves = 2 prow x 4 kcol
    const int lane = t & 63, w = t >> 6;
    const int wy = lane >> 3, wx = lane & 7;
    const int wr = w >> 2,    wc = w & 3;
    const int pl0 = wr * 64 + wy * 8;     // 0..120
    const int kc0 = wc * 64 + wx * 4;     // scattered: group g at +g*32

    float bv[8]; int bk[8]; float xnr[8];
#pragma unroll
    for (int i = 0; i < 8; ++i) { bv[i] = 1e30f; bk[i] = 0; }

    for (int ch = 0; ch < NCHUNK; ++ch) {
        // write staged tile to cs[d][k] (k lane-fast b32: 2-way alias, free)
#pragma unroll
        for (int i = 0; i < 8; ++i) {
            int fidx = i * 512 + t;
            int k = fidx & 255, dq = fidx >> 8;
            cs[(4 * dq + 0) * CHUNK + k] = creg[i].x;
            cs[(4 * dq + 1) * CHUNK + k] = creg[i].y;
            cs[(4 * dq + 2) * CHUNK + k] = creg[i].z;
            cs[(4 * dq + 3) * CHUNK + k] = creg[i].w;
        }
        if (ch + 1 < NCHUNK) {            // prefetch next chunk under compute
#pragma unroll
            for (int i = 0; i < 8; ++i) {
                int fidx = i * 512 + t;
                int k = fidx & 255, dq = fidx >> 8;
                creg[i] = cb4[(size_t)((ch + 1) * CHUNK + k) * 16 + dq];
            }
        }
        __syncthreads();                  // cs ready (xn too, on first pass)

        if (ch == 0) {
#pragma unroll
            for (int i = 0; i < 8; ++i) xnr[i] = xn[pl0 + i];
        }

        float acc[8][8];                  // j = g*4 + e
#pragma unroll
        for (int i = 0; i < 8; ++i)
#pragma unroll
            for (int j = 0; j < 8; ++j) acc[i][j] = 0.f;

#pragma unroll 4
        for (int d = 0; d < DIM; ++d) {
            const float* xr = xs + d * BPIX + pl0;
            const float* cr = cs + d * CHUNK + kc0;
            float4 xlo = *reinterpret_cast<const float4*>(xr);
            float4 xhi = *reinterpret_cast<const float4*>(xr + 4);
            float4 cfA = *reinterpret_cast<const float4*>(cr);        // g=0
            float4 cfB = *reinterpret_cast<const float4*>(cr + 32);   // g=1
#define ROW(i, xi) \
            acc[i][0] = fmaf(xi, cfA.x, acc[i][0]); \
            acc[i][1] = fmaf(xi, cfA.y, acc[i][1]); \
            acc[i][2] = fmaf(xi, cfA.z, acc[i][2]); \
            acc[i][3] = fmaf(xi, cfA.w, acc[i][3]); \
            acc[i][4] = fmaf(xi, cfB.x, acc[i][4]); \
            acc[i][5] = fmaf(xi, cfB.y, acc[i][5]); \
            acc[i][6] = fmaf(xi, cfB.z, acc[i][6]); \
            acc[i][7] = fmaf(xi, cfB.w, acc[i][7]);
            ROW(0, xlo.x) ROW(1, xlo.y) ROW(2, xlo.z) ROW(3, xlo.w)
            ROW(4, xhi.x) ROW(5, xhi.y) ROW(6, xhi.z) ROW(7, xhi.w)
#undef ROW
        }

        // chunk epilogue: reference rounding (xn - 2*dot) + c2 (exact r2-r11);
        // k ascending within thread across chunks -> strict < = first-min.
        int kg = ch * CHUNK + kc0;
        float4 c2A = *reinterpret_cast<const float4*>(&c2[kg]);
        float4 c2B = *reinterpret_cast<const float4*>(&c2[kg + 32]);
        float c2a[8] = {c2A.x, c2A.y, c2A.z, c2A.w, c2B.x, c2B.y, c2B.z, c2B.w};
#pragma unroll
        for (int i = 0; i < 8; ++i) {
#pragma unroll
            for (int j = 0; j < 8; ++j) {
                float dist = (xnr[i] - 2.0f * acc[i][j]) + c2a[j];
                int   k    = kg + (j >> 2) * 32 + (j & 3);
                if (dist < bv[i]) { bv[i] = dist; bk[i] = k; }
            }
        }
        __syncthreads();                  // all reads of cs done before overwrite
    }

    // ---- cross-wx shuffle reduce: lex (val,k) == global first-min
#pragma unroll
    for (int i = 0; i < 8; ++i) {
#pragma unroll
        for (int off = 1; off <= 4; off <<= 1) {
            float ov = __shfl_xor(bv[i], off);
            int   ok = __shfl_xor(bk[i], off);
            if (ov < bv[i] || (ov == bv[i] && ok < bk[i])) { bv[i] = ov; bk[i] = ok; }
        }
    }
    if (wx == 0) {
#pragma unroll
        for (int i = 0; i < 8; ++i)
            red[wc][pl0 + i] = make_float2(bv[i], __int_as_float(bk[i]));
    }
    __syncthreads();

    // ---- merge 4 code-quarters (wc ascending = k ascending: lex), emit idx
    if (t < BPIX) {
        float fv = 1e30f; int fk = 0;
#pragma unroll
        for (int cc = 0; cc < 4; ++cc) {
            float2 r  = red[cc][t];
            int    rk = __float_as_int(r.y);
            if (r.x < fv || (r.x == fv && rk < fk)) { fv = r.x; fk = rk; }
        }
        sidx[t] = fk;
        idx[p_base + t] = fk;
    }
    __syncthreads();

    // ---- fused quantized write: all 512 threads; r = t&127 lane-fast so each
    // 128-lane run stores consecutive hw -> coalesced. 16 dims per thread.
    {
        int r = t & 127, q = t >> 7;      // q = dim quarter
        int fk = sidx[r];
        const float4* crow = cb4 + (size_t)fk * 16 + q * 4;
        float* qb = quant + (size_t)bb * (DIM * 1024) + (size_t)(q * 16) * 1024
                    + (hw0 + r);
#pragma unroll
        for (int dq = 0; dq < 4; ++dq) {
            float4 cv = crow[dq];
            qb[(size_t)(dq * 4 + 0) << 10] = cv.x;
            qb[(size_t)(dq * 4 + 1) << 10] = cv.y;
            qb[(size_t)(dq * 4 + 2) << 10] = cv.z;
            qb[(size_t)(dq * 4 + 3) << 10] = cv.w;
        }
    }
}

// Streaming one-hot writer: flat float4 index e covers enc[n][j0..j0+3],
// n = e>>8, j0 = (e&255)*4. grid-stride, 2048 blocks.
__global__ __launch_bounds__(256) void enc_write(const int* __restrict__ idx,
                                                 float* __restrict__ enc) {
    const int TOT = (N_PIX / 4) * K_CODES;   // 8388608 float4s
    int tid = blockIdx.x * 256 + threadIdx.x;
    float4* enc4 = reinterpret_cast<float4*>(enc);
    for (int e = tid; e < TOT; e += 2048 * 256) {
        int n  = e >> 8;
        int j0 = (e & 255) << 2;
        int ir = idx[n];                 // row-uniform -> L1/L2 broadcast
        float4 v;
        v.x = (ir == j0 + 0) ? 1.0f : 0.0f;
        v.y = (ir == j0 + 1) ? 1.0f : 0.0f;
        v.z = (ir == j0 + 2) ? 1.0f : 0.0f;
        v.w = (ir == j0 + 3) ? 1.0f : 0.0f;
        enc4[e] = v;
    }
}

extern "C" void kernel_launch(void* const* d_in, const int* in_sizes, int n_in,
                              void* d_out, int out_size, void* d_ws, size_t ws_size,
                              hipStream_t stream) {
    const float* x  = (const float*)d_in[0];
    const float* cb = (const float*)d_in[1];

    float* c2  = (float*)d_ws;
    int*   idx = (int*)((char*)d_ws + 4096);

    float* enc   = (float*)d_out;                           // [32768, 1024]
    float* quant = (float*)d_out + (size_t)N_PIX * K_CODES; // [32, 64, 32, 32]

    c2_kernel<<<K_CODES / 256, 256, 0, stream>>>(cb, c2);
    argmin_tile<<<N_PIX / BPIX, 512, 0, stream>>>(x, cb, c2, idx, quant);
    enc_write<<<2048, 256, 0, stream>>>(idx, enc);
}